// Round 13
// baseline (61.791 us; speedup 1.0000x reference)
//
#include <hip/hip_runtime.h>
#include <math.h>

#define BB 16
#define NN 96
#define HH 256
#define NBIN 11
#define NBPAD 12   // bin row padded to 12 floats
#define IB 2       // i's per compute block

// ---------------------------------------------------------------------------
// DPP wave64 sum -> wave-uniform scalar. Pure VALU.
// ---------------------------------------------------------------------------
template <int CTRL>
__device__ __forceinline__ float dpp_add(float x) {
    int t = __builtin_amdgcn_update_dpp(0, __float_as_int(x),
                                        CTRL, 0xf, 0xf, true);
    return x + __int_as_float(t);
}

__device__ __forceinline__ float wave64_sum_uniform(float x) {
    x = dpp_add<0x111>(x);  // row_shr:1
    x = dpp_add<0x112>(x);  // row_shr:2
    x = dpp_add<0x114>(x);  // row_shr:4
    x = dpp_add<0x118>(x);  // row_shr:8
    x = dpp_add<0x142>(x);  // row_bcast:15
    x = dpp_add<0x143>(x);  // row_bcast:31
    return __int_as_float(__builtin_amdgcn_readlane(__float_as_int(x), 63));
}

// ---------------------------------------------------------------------------
// Kernel 1: proj[r][k] = sum_h inputs[r][h] * W_atom[h][k] + 0.5*b_bin[k]
// ---------------------------------------------------------------------------
#define ROWS_PER_BLOCK 3

__global__ __launch_bounds__(HH) void proj_kernel(
    const float* __restrict__ inputs,
    const float* __restrict__ W_atom,
    const float* __restrict__ b_bin,
    float* __restrict__ proj)
{
    __shared__ float rows[ROWS_PER_BLOCK][HH];
    const int r0 = blockIdx.x * ROWS_PER_BLOCK;
    const int k  = threadIdx.x;

    #pragma unroll
    for (int r = 0; r < ROWS_PER_BLOCK; ++r)
        rows[r][k] = inputs[(size_t)(r0 + r) * HH + k];
    __syncthreads();

    float acc[ROWS_PER_BLOCK];
    #pragma unroll
    for (int r = 0; r < ROWS_PER_BLOCK; ++r) acc[r] = 0.f;

    #pragma unroll 8
    for (int h = 0; h < HH; ++h) {
        const float w = W_atom[(size_t)h * HH + k];
        #pragma unroll
        for (int r = 0; r < ROWS_PER_BLOCK; ++r)
            acc[r] = fmaf(rows[r][h], w, acc[r]);
    }

    const float halfb = 0.5f * b_bin[k];
    #pragma unroll
    for (int r = 0; r < ROWS_PER_BLOCK; ++r)
        proj[(size_t)(r0 + r) * HH + k] = acc[r] + halfb;
}

// ---------------------------------------------------------------------------
// Kernel 2 — heterogeneous-role mega kernel, 2304 blocks.
//   g = blockIdx/3, r = blockIdx%3.
//   r<2 : WRITER block for bi = 2*g + r — pure streaming (loads+stores only
//         in its FIFOs, R5's proven ~5 TB/s pattern, no barriers after stage).
//   r==2: COMPUTE block for {2g, 2g+1} (IB=2) — score+context, NO bulk
//         stores. Roles interleave in dispatch order so every CU runs a mix;
//         store drain and compute overlap at CU level with no coupling.
// ---------------------------------------------------------------------------
__global__ __launch_bounds__(256) void pair_ctx_kernel(
    const float* __restrict__ inputs,
    const float* __restrict__ bin_features,
    const float* __restrict__ W_bin,
    const float* __restrict__ w_score,
    const float* __restrict__ b_score,
    const float* __restrict__ proj,
    float* __restrict__ atom_pair,
    float* __restrict__ context)
{
    const int g    = blockIdx.x / 3;
    const int role = blockIdx.x % 3;
    const int lane = threadIdx.x & 63;
    const int wave = threadIdx.x >> 6;     // 0..3
    const int k4   = lane << 2;

    if (role < 2) {
        // ---------------- WRITER: atom_pair rows for one bi ----------------
        const int bi = 2 * g + role;
        const int b  = bi / NN;
        const float4 in_i = *(const float4*)(inputs + (size_t)bi * HH + k4);
        const float* inb  = inputs + (size_t)b * NN * HH + k4;
        float*       apb  = atom_pair + (size_t)bi * NN * HH + k4;

        for (int t = 0; t < 6; ++t) {
            const int j0 = wave + 16 * t;  // j0, j0+4, j0+8, j0+12
            float4 r4[4];
            #pragma unroll
            for (int u = 0; u < 4; ++u)
                r4[u] = *(const float4*)(inb + (size_t)(j0 + 4 * u) * HH);
            #pragma unroll
            for (int u = 0; u < 4; ++u) {
                float4 ap;
                ap.x = in_i.x + r4[u].x;  ap.y = in_i.y + r4[u].y;
                ap.z = in_i.z + r4[u].z;  ap.w = in_i.w + r4[u].w;
                *(float4*)(apb + (size_t)(j0 + 4 * u) * HH) = ap;
            }
        }
        return;
    }

    // ---------------- COMPUTE: score + context for {2g, 2g+1} --------------
    const int bi0 = 2 * g;
    const int b   = bi0 / NN;

    __shared__ float binf[IB * NN * NBPAD];
    __shared__ float partial[3][IB * HH];

    {
        const float* bp = bin_features + (size_t)bi0 * NN * NBIN;
        for (int t = threadIdx.x; t < IB * NN * NBIN; t += 256)
            binf[(t / NBIN) * NBPAD + (t % NBIN)] = bp[t];
    }

    const float4 pr_i0 = *(const float4*)(proj + (size_t)bi0 * HH + k4);
    const float4 pr_i1 = *(const float4*)(proj + (size_t)(bi0 + 1) * HH + k4);
    const float4 ws    = *(const float4*)(w_score + k4);
    const float  bsc   = b_score[0];

    float4 wb[NBIN];
    #pragma unroll
    for (int c = 0; c < NBIN; ++c)
        wb[c] = *(const float4*)(W_bin + c * HH + k4);

    const float* inb = inputs + (size_t)b * NN * HH + k4;
    const float* prb = proj   + (size_t)b * NN * HH + k4;

    __syncthreads();                       // binf ready

    float4 acc0 = make_float4(0.f, 0.f, 0.f, 0.f);
    float4 acc1 = make_float4(0.f, 0.f, 0.f, 0.f);

    for (int t = 0; t < 12; ++t) {
        const int j0 = wave + 8 * t;       // j's: j0, j0+4

        float4 inj[2], prj[2];
        #pragma unroll
        for (int u = 0; u < 2; ++u) {
            inj[u] = *(const float4*)(inb + (size_t)(j0 + 4 * u) * HH);
            prj[u] = *(const float4*)(prb + (size_t)(j0 + 4 * u) * HH);
        }

        float part[4];                     // [2u+ii]
        #pragma unroll
        for (int u = 0; u < 2; ++u) {
            const int j = j0 + 4 * u;
            #pragma unroll
            for (int ii = 0; ii < 2; ++ii) {
                const float4* bf4 =
                    (const float4*)&binf[(ii * NN + j) * NBPAD];
                const float4 bq0 = bf4[0];
                const float4 bq1 = bf4[1];
                const float4 bq2 = bf4[2];
                const float bc[NBIN] = { bq0.x, bq0.y, bq0.z, bq0.w,
                                         bq1.x, bq1.y, bq1.z, bq1.w,
                                         bq2.x, bq2.y, bq2.z };

                const float4 pri = ii ? pr_i1 : pr_i0;
                float4 v;
                v.x = pri.x + prj[u].x;  v.y = pri.y + prj[u].y;
                v.z = pri.z + prj[u].z;  v.w = pri.w + prj[u].w;
                #pragma unroll
                for (int c = 0; c < NBIN; ++c) {
                    v.x = fmaf(bc[c], wb[c].x, v.x);
                    v.y = fmaf(bc[c], wb[c].y, v.y);
                    v.z = fmaf(bc[c], wb[c].z, v.z);
                    v.w = fmaf(bc[c], wb[c].w, v.w);
                }
                v.x = fmaxf(v.x, 0.f); v.y = fmaxf(v.y, 0.f);
                v.z = fmaxf(v.z, 0.f); v.w = fmaxf(v.w, 0.f);
                part[2 * u + ii] =
                    v.x * ws.x + v.y * ws.y + v.z * ws.z + v.w * ws.w;
            }
        }

        float s[4];
        #pragma unroll
        for (int p = 0; p < 4; ++p) {
            const float tot = wave64_sum_uniform(part[p]);
            // fast sigmoid: v_rcp_f32 (abs err ~1ulp; absmax headroom 10x)
            s[p] = __builtin_amdgcn_rcpf(1.f + __expf(-(tot + bsc)));
        }

        #pragma unroll
        for (int u = 0; u < 2; ++u) {
            acc0.x = fmaf(s[2 * u],     inj[u].x, acc0.x);
            acc0.y = fmaf(s[2 * u],     inj[u].y, acc0.y);
            acc0.z = fmaf(s[2 * u],     inj[u].z, acc0.z);
            acc0.w = fmaf(s[2 * u],     inj[u].w, acc0.w);
            acc1.x = fmaf(s[2 * u + 1], inj[u].x, acc1.x);
            acc1.y = fmaf(s[2 * u + 1], inj[u].y, acc1.y);
            acc1.z = fmaf(s[2 * u + 1], inj[u].z, acc1.z);
            acc1.w = fmaf(s[2 * u + 1], inj[u].w, acc1.w);
        }
    }

    if (wave > 0) {
        *(float4*)(&partial[wave - 1][k4]) = acc0;
        *(float4*)(&partial[wave - 1][HH + k4]) = acc1;
    }
    __syncthreads();
    if (wave == 0) {
        #pragma unroll
        for (int w = 0; w < 3; ++w) {
            const float4 p0 = *(const float4*)(&partial[w][k4]);
            const float4 p1 = *(const float4*)(&partial[w][HH + k4]);
            acc0.x += p0.x; acc0.y += p0.y; acc0.z += p0.z; acc0.w += p0.w;
            acc1.x += p1.x; acc1.y += p1.y; acc1.z += p1.z; acc1.w += p1.w;
        }
        *(float4*)(context + (size_t)bi0 * HH + k4) = acc0;
        *(float4*)(context + (size_t)(bi0 + 1) * HH + k4) = acc1;
    }
}

extern "C" void kernel_launch(void* const* d_in, const int* in_sizes, int n_in,
                              void* d_out, int out_size, void* d_ws, size_t ws_size,
                              hipStream_t stream)
{
    const float* inputs       = (const float*)d_in[0];   // (B,N,H)
    const float* bin_features = (const float*)d_in[1];   // (B,N,N,BIN)
    const float* W_atom       = (const float*)d_in[2];   // (H,H)
    const float* W_bin        = (const float*)d_in[3];   // (BIN,H)
    const float* b_bin        = (const float*)d_in[4];   // (H,)
    const float* w_score      = (const float*)d_in[5];   // (H,1)
    const float* b_score      = (const float*)d_in[6];   // (1,)

    float* context   = (float*)d_out;                         // B*N*H
    float* atom_pair = (float*)d_out + (size_t)BB * NN * HH;  // B*N*N*H

    float* proj = (float*)d_ws;                               // B*N*H floats

    proj_kernel<<<(BB * NN) / ROWS_PER_BLOCK, HH, 0, stream>>>(
        inputs, W_atom, b_bin, proj);

    // 2304 blocks: per triple {writer bi=2g, writer bi=2g+1, compute {2g,2g+1}}
    pair_ctx_kernel<<<(BB * NN / 2) * 3, 256, 0, stream>>>(
        inputs, bin_features, W_bin, w_score, b_score, proj,
        atom_pair, context);
}

// Round 14
// 48.981 us; speedup vs baseline: 1.2615x; 1.2615x over previous
//
#include <hip/hip_runtime.h>
#include <math.h>

#define BB 16
#define NN 96
#define HH 256
#define NBIN 11
#define NBPAD 12   // bin row padded to 12 floats
#define IB 2       // i's per block (load amortization)

typedef float f32x4 __attribute__((ext_vector_type(4)));

// ---------------------------------------------------------------------------
// DPP wave64 sum -> wave-uniform scalar. Pure VALU.
// ---------------------------------------------------------------------------
template <int CTRL>
__device__ __forceinline__ float dpp_add(float x) {
    int t = __builtin_amdgcn_update_dpp(0, __float_as_int(x),
                                        CTRL, 0xf, 0xf, true);
    return x + __int_as_float(t);
}

__device__ __forceinline__ float wave64_sum_uniform(float x) {
    x = dpp_add<0x111>(x);  // row_shr:1
    x = dpp_add<0x112>(x);  // row_shr:2
    x = dpp_add<0x114>(x);  // row_shr:4
    x = dpp_add<0x118>(x);  // row_shr:8
    x = dpp_add<0x142>(x);  // row_bcast:15
    x = dpp_add<0x143>(x);  // row_bcast:31
    return __int_as_float(__builtin_amdgcn_readlane(__float_as_int(x), 63));
}

// ---------------------------------------------------------------------------
// Kernel 1: proj[r][k] = sum_h inputs[r][h] * W_atom[h][k] + 0.5*b_bin[k]
// ---------------------------------------------------------------------------
#define ROWS_PER_BLOCK 3

__global__ __launch_bounds__(HH) void proj_kernel(
    const float* __restrict__ inputs,
    const float* __restrict__ W_atom,
    const float* __restrict__ b_bin,
    float* __restrict__ proj)
{
    __shared__ float rows[ROWS_PER_BLOCK][HH];
    const int r0 = blockIdx.x * ROWS_PER_BLOCK;
    const int k  = threadIdx.x;

    #pragma unroll
    for (int r = 0; r < ROWS_PER_BLOCK; ++r)
        rows[r][k] = inputs[(size_t)(r0 + r) * HH + k];
    __syncthreads();

    float acc[ROWS_PER_BLOCK];
    #pragma unroll
    for (int r = 0; r < ROWS_PER_BLOCK; ++r) acc[r] = 0.f;

    #pragma unroll 8
    for (int h = 0; h < HH; ++h) {
        const float w = W_atom[(size_t)h * HH + k];
        #pragma unroll
        for (int r = 0; r < ROWS_PER_BLOCK; ++r)
            acc[r] = fmaf(rows[r][h], w, acc[r]);
    }

    const float halfb = 0.5f * b_bin[k];
    #pragma unroll
    for (int r = 0; r < ROWS_PER_BLOCK; ++r)
        proj[(size_t)(r0 + r) * HH + k] = acc[r] + halfb;
}

// ---------------------------------------------------------------------------
// Kernel 2 (fused pair + score + context), i-blocked IB=2 (R12 structure,
//   best so far) with ONE isolated change: NONTEMPORAL atom_pair stores.
//   atom_pair is write-once-never-read; bypassing L2 keeps inputs/proj/bin
//   resident (R1 measured 2.4x read over-fetch with cached stores).
// ---------------------------------------------------------------------------
__global__ __launch_bounds__(256, 4) void pair_ctx_kernel(
    const float* __restrict__ inputs,
    const float* __restrict__ bin_features,
    const float* __restrict__ W_bin,
    const float* __restrict__ w_score,
    const float* __restrict__ b_score,
    const float* __restrict__ proj,
    float* __restrict__ atom_pair,
    float* __restrict__ context)
{
    const int blk  = blockIdx.x;           // 0 .. BB*NN/IB-1
    const int b    = blk / (NN / IB);
    const int ip   = blk % (NN / IB);
    const int bi0  = b * NN + IB * ip;     // and bi0+1
    const int lane = threadIdx.x & 63;
    const int wave = threadIdx.x >> 6;     // 0..3
    const int k4   = lane << 2;            // float4 offset into H

    __shared__ float binf[IB * NN * NBPAD];      // padded rows for both i's
    __shared__ float partial[3][IB * HH];        // cross-wave context combine

    {   // both i's bin rows are contiguous in global: one 8448 B copy
        const float* bp = bin_features + (size_t)bi0 * NN * NBIN;
        for (int t = threadIdx.x; t < IB * NN * NBIN; t += 256)
            binf[(t / NBIN) * NBPAD + (t % NBIN)] = bp[t];
    }

    const float4 in_i0 = *(const float4*)(inputs + (size_t)bi0 * HH + k4);
    const float4 in_i1 = *(const float4*)(inputs + (size_t)(bi0 + 1) * HH + k4);
    const float4 pr_i0 = *(const float4*)(proj   + (size_t)bi0 * HH + k4);
    const float4 pr_i1 = *(const float4*)(proj   + (size_t)(bi0 + 1) * HH + k4);
    const float4 ws    = *(const float4*)(w_score + k4);
    const float  bsc   = b_score[0];

    float4 wb[NBIN];
    #pragma unroll
    for (int c = 0; c < NBIN; ++c)
        wb[c] = *(const float4*)(W_bin + c * HH + k4);

    const float* inb  = inputs + (size_t)b * NN * HH + k4;
    const float* prb  = proj   + (size_t)b * NN * HH + k4;
    float*       apb0 = atom_pair + (size_t)bi0 * NN * HH + k4;
    float*       apb1 = atom_pair + (size_t)(bi0 + 1) * NN * HH + k4;

    __syncthreads();                       // binf ready

    float4 acc0 = make_float4(0.f, 0.f, 0.f, 0.f);
    float4 acc1 = make_float4(0.f, 0.f, 0.f, 0.f);

    // j = wave + 4*u + 8*t, u in {0,1}, t in [0,12) covers [0,96)
    for (int t = 0; t < 12; ++t) {
        const int j0 = wave + 8 * t;       // j's this step: j0, j0+4

        float4 inj[2], prj[2];
        #pragma unroll
        for (int u = 0; u < 2; ++u) {
            inj[u] = *(const float4*)(inb + (size_t)(j0 + 4 * u) * HH);
            prj[u] = *(const float4*)(prb + (size_t)(j0 + 4 * u) * HH);
        }

        #pragma unroll
        for (int u = 0; u < 2; ++u) {
            f32x4 ap;
            ap.x = in_i0.x + inj[u].x;  ap.y = in_i0.y + inj[u].y;
            ap.z = in_i0.z + inj[u].z;  ap.w = in_i0.w + inj[u].w;
            __builtin_nontemporal_store(
                ap, (f32x4*)(apb0 + (size_t)(j0 + 4 * u) * HH));
            ap.x = in_i1.x + inj[u].x;  ap.y = in_i1.y + inj[u].y;
            ap.z = in_i1.z + inj[u].z;  ap.w = in_i1.w + inj[u].w;
            __builtin_nontemporal_store(
                ap, (f32x4*)(apb1 + (size_t)(j0 + 4 * u) * HH));
        }

        float part[4];                     // [2u+ii]
        #pragma unroll
        for (int u = 0; u < 2; ++u) {
            const int j = j0 + 4 * u;
            #pragma unroll
            for (int ii = 0; ii < 2; ++ii) {
                const float4* bf4 =
                    (const float4*)&binf[(ii * NN + j) * NBPAD];
                const float4 bq0 = bf4[0];
                const float4 bq1 = bf4[1];
                const float4 bq2 = bf4[2];
                const float bc[NBIN] = { bq0.x, bq0.y, bq0.z, bq0.w,
                                         bq1.x, bq1.y, bq1.z, bq1.w,
                                         bq2.x, bq2.y, bq2.z };

                const float4 pri = ii ? pr_i1 : pr_i0;
                float4 v;
                v.x = pri.x + prj[u].x;  v.y = pri.y + prj[u].y;
                v.z = pri.z + prj[u].z;  v.w = pri.w + prj[u].w;
                #pragma unroll
                for (int c = 0; c < NBIN; ++c) {
                    v.x = fmaf(bc[c], wb[c].x, v.x);
                    v.y = fmaf(bc[c], wb[c].y, v.y);
                    v.z = fmaf(bc[c], wb[c].z, v.z);
                    v.w = fmaf(bc[c], wb[c].w, v.w);
                }
                v.x = fmaxf(v.x, 0.f); v.y = fmaxf(v.y, 0.f);
                v.z = fmaxf(v.z, 0.f); v.w = fmaxf(v.w, 0.f);
                part[2 * u + ii] =
                    v.x * ws.x + v.y * ws.y + v.z * ws.z + v.w * ws.w;
            }
        }

        // four independent DPP reduce chains (2 j x 2 i), pure VALU
        float s[4];
        #pragma unroll
        for (int p = 0; p < 4; ++p) {
            const float tot = wave64_sum_uniform(part[p]);
            s[p] = __builtin_amdgcn_rcpf(1.f + __expf(-(tot + bsc)));
        }

        #pragma unroll
        for (int u = 0; u < 2; ++u) {
            acc0.x = fmaf(s[2 * u],     inj[u].x, acc0.x);
            acc0.y = fmaf(s[2 * u],     inj[u].y, acc0.y);
            acc0.z = fmaf(s[2 * u],     inj[u].z, acc0.z);
            acc0.w = fmaf(s[2 * u],     inj[u].w, acc0.w);
            acc1.x = fmaf(s[2 * u + 1], inj[u].x, acc1.x);
            acc1.y = fmaf(s[2 * u + 1], inj[u].y, acc1.y);
            acc1.z = fmaf(s[2 * u + 1], inj[u].z, acc1.z);
            acc1.w = fmaf(s[2 * u + 1], inj[u].w, acc1.w);
        }
    }

    // cross-wave reduce of both context accumulators
    if (wave > 0) {
        *(float4*)(&partial[wave - 1][k4]) = acc0;
        *(float4*)(&partial[wave - 1][HH + k4]) = acc1;
    }
    __syncthreads();
    if (wave == 0) {
        #pragma unroll
        for (int w = 0; w < 3; ++w) {
            const float4 p0 = *(const float4*)(&partial[w][k4]);
            const float4 p1 = *(const float4*)(&partial[w][HH + k4]);
            acc0.x += p0.x; acc0.y += p0.y; acc0.z += p0.z; acc0.w += p0.w;
            acc1.x += p1.x; acc1.y += p1.y; acc1.z += p1.z; acc1.w += p1.w;
        }
        *(float4*)(context + (size_t)bi0 * HH + k4) = acc0;
        *(float4*)(context + (size_t)(bi0 + 1) * HH + k4) = acc1;
    }
}

extern "C" void kernel_launch(void* const* d_in, const int* in_sizes, int n_in,
                              void* d_out, int out_size, void* d_ws, size_t ws_size,
                              hipStream_t stream)
{
    const float* inputs       = (const float*)d_in[0];   // (B,N,H)
    const float* bin_features = (const float*)d_in[1];   // (B,N,N,BIN)
    const float* W_atom       = (const float*)d_in[2];   // (H,H)
    const float* W_bin        = (const float*)d_in[3];   // (BIN,H)
    const float* b_bin        = (const float*)d_in[4];   // (H,)
    const float* w_score      = (const float*)d_in[5];   // (H,1)
    const float* b_score      = (const float*)d_in[6];   // (1,)

    float* context   = (float*)d_out;                         // B*N*H
    float* atom_pair = (float*)d_out + (size_t)BB * NN * HH;  // B*N*N*H

    float* proj = (float*)d_ws;                               // B*N*H floats

    proj_kernel<<<(BB * NN) / ROWS_PER_BLOCK, HH, 0, stream>>>(
        inputs, W_atom, b_bin, proj);

    pair_ctx_kernel<<<(BB * NN) / IB, 256, 0, stream>>>(
        inputs, bin_features, W_bin, w_score, b_score, proj,
        atom_pair, context);
}